// Round 1
// baseline (7070.110 us; speedup 1.0000x reference)
//
#include <hip/hip_runtime.h>
#include <cmath>

#define NB 16
#define TSEQ 1024
#define DIN 16
#define DM 512
#define DFFN 2048
#define NHEADS 8
#define DHEAD 64
#define NLAYERS 4
#define DOUTN 3
#define ROWS (NB*TSEQ)   /* 16384 */

// ---------------------------------------------------------------- encode
// h[row][d] = (x[row] @ enc_W + enc_b)[d] * sqrt(512) + pe(t,d)*(pad!=0)
__global__ __launch_bounds__(128) void encode_kernel(
    const float* __restrict__ x, const int* __restrict__ pad,
    const float* __restrict__ W, const float* __restrict__ b,
    float* __restrict__ h)
{
    int row = blockIdx.x;          // 0..16383  (row = batch*1024 + t)
    int t   = row & (TSEQ - 1);
    int c   = threadIdx.x * 4;     // 128 threads * 4 cols = 512
    float acc[4];
    #pragma unroll
    for (int j = 0; j < 4; ++j) acc[j] = b[c + j];
    const float* xr = x + (size_t)row * DIN;
    #pragma unroll
    for (int k = 0; k < DIN; ++k) {
        float xv = xr[k];
        const float* wr = W + (size_t)k * DM + c;
        #pragma unroll
        for (int j = 0; j < 4; ++j) acc[j] += xv * wr[j];
    }
    const float s = 22.62741699796952f;  // sqrt(512)
    bool has_pe = (pad[row] != 0);
    #pragma unroll
    for (int j = 0; j < 4; ++j) {
        acc[j] *= s;
        if (has_pe) {
            int d = c + j;
            float base = (float)t * powf(10000.0f, -(float)d * (1.0f/512.0f));
            float pe = ((d & 1) == 0) ? sinf(base) : cosf(base);
            acc[j] += pe;
        }
    }
    float4 o = make_float4(acc[0], acc[1], acc[2], acc[3]);
    *(float4*)&h[(size_t)row * DM + c] = o;
}

// ---------------------------------------------------------------- GEMM
// C(MxN) = A(MxK) @ B(KxN) [+bias] [relu].  64x64 tile, BK=16, 256 thr, 4x4 micro.
template<int RELU>
__global__ __launch_bounds__(256) void gemm_f32(
    const float* __restrict__ A, const float* __restrict__ B,
    const float* __restrict__ bias, float* __restrict__ C,
    int M, int N, int K)
{
    __shared__ float As[16][68];   // [k][m], stride 68 -> 16B aligned rows
    __shared__ float Bs[16][68];   // [k][n]
    const int tid = threadIdx.x;
    const int bm = blockIdx.x * 64;
    const int bn = blockIdx.y * 64;
    const int tx = tid & 15, ty = tid >> 4;
    const int arow = tid >> 2, akq = (tid & 3) * 4;
    const float* Ap = A + (size_t)(bm + arow) * K + akq;
    const float* Bp = B + (size_t)ty * N + bn + tx * 4;
    float acc[4][4] = {};
    for (int k0 = 0; k0 < K; k0 += 16) {
        float4 av = *(const float4*)(Ap + k0);
        float4 bv = *(const float4*)(Bp + (size_t)k0 * N);
        As[akq + 0][arow] = av.x;
        As[akq + 1][arow] = av.y;
        As[akq + 2][arow] = av.z;
        As[akq + 3][arow] = av.w;
        *(float4*)&Bs[ty][tx * 4] = bv;
        __syncthreads();
        #pragma unroll
        for (int kk = 0; kk < 16; ++kk) {
            float4 a = *(const float4*)&As[kk][ty * 4];
            float4 bq = *(const float4*)&Bs[kk][tx * 4];
            acc[0][0] += a.x * bq.x; acc[0][1] += a.x * bq.y; acc[0][2] += a.x * bq.z; acc[0][3] += a.x * bq.w;
            acc[1][0] += a.y * bq.x; acc[1][1] += a.y * bq.y; acc[1][2] += a.y * bq.z; acc[1][3] += a.y * bq.w;
            acc[2][0] += a.z * bq.x; acc[2][1] += a.z * bq.y; acc[2][2] += a.z * bq.z; acc[2][3] += a.z * bq.w;
            acc[3][0] += a.w * bq.x; acc[3][1] += a.w * bq.y; acc[3][2] += a.w * bq.z; acc[3][3] += a.w * bq.w;
        }
        __syncthreads();
    }
    float bb[4] = {0.f, 0.f, 0.f, 0.f};
    if (bias) {
        #pragma unroll
        for (int j = 0; j < 4; ++j) bb[j] = bias[bn + tx * 4 + j];
    }
    #pragma unroll
    for (int i = 0; i < 4; ++i) {
        float4 o;
        o.x = acc[i][0] + bb[0];
        o.y = acc[i][1] + bb[1];
        o.z = acc[i][2] + bb[2];
        o.w = acc[i][3] + bb[3];
        if (RELU) {
            o.x = fmaxf(o.x, 0.f); o.y = fmaxf(o.y, 0.f);
            o.z = fmaxf(o.z, 0.f); o.w = fmaxf(o.w, 0.f);
        }
        *(float4*)&C[(size_t)(bm + ty * 4 + i) * N + bn + tx * 4] = o;
    }
}

// ---------------------------------------------------------------- attention
// Per token: Qh(64x8)@Kh(8x64)/32 -> mask -> softmax rows -> @Vh(64x8) -> out 512
// One wave per token; lane = energy row i. O may alias V (block reads own V first).
__global__ __launch_bounds__(64) void attn_kernel(
    const float* __restrict__ Q, const float* __restrict__ K,
    const float* __restrict__ V, const int* __restrict__ pad,
    float* __restrict__ O)
{
    int site = blockIdx.x;
    int lane = threadIdx.x;
    __shared__ float qs[512], ks[512], vs[512];
    const float* qp = Q + (size_t)site * DM;
    const float* kp = K + (size_t)site * DM;
    const float* vp = V + (size_t)site * DM;
    #pragma unroll
    for (int j = 0; j < 8; ++j) {
        qs[lane + 64 * j] = qp[lane + 64 * j];
        ks[lane + 64 * j] = kp[lane + 64 * j];
        vs[lane + 64 * j] = vp[lane + 64 * j];
    }
    __syncthreads();
    float qr[8];
    #pragma unroll
    for (int j = 0; j < 8; ++j) qr[j] = qs[j * 64 + lane];
    float e[64];
    float m = -1e30f;
    #pragma unroll
    for (int k2 = 0; k2 < 64; ++k2) {
        float s = 0.f;
        #pragma unroll
        for (int j = 0; j < 8; ++j) s += qr[j] * ks[j * 64 + k2];
        s *= (1.0f / 32.0f);   // / (D_HEAD/2)
        e[k2] = s;
        m = fmaxf(m, s);
    }
    bool masked = (pad[site] == 0);
    float sum = 0.f;
    #pragma unroll
    for (int k2 = 0; k2 < 64; ++k2) {
        float p = masked ? 1.0f : __expf(e[k2] - m);
        e[k2] = p;
        sum += p;
    }
    float inv = 1.0f / sum;
    float o[8] = {0.f,0.f,0.f,0.f,0.f,0.f,0.f,0.f};
    #pragma unroll
    for (int k2 = 0; k2 < 64; ++k2) {
        float p = e[k2] * inv;
        #pragma unroll
        for (int j = 0; j < 8; ++j) o[j] += p * vs[j * 64 + k2];
    }
    #pragma unroll
    for (int j = 0; j < 8; ++j)
        O[(size_t)site * DM + lane * 8 + j] = o[j];
}

// ---------------------------------------------------------------- add + layernorm
// h[row] = LN(a[row] + h[row]) * g + b.  One wave per row, 4 rows / block.
__global__ __launch_bounds__(256) void add_ln_kernel(
    const float* __restrict__ A, float* __restrict__ H,
    const float* __restrict__ g, const float* __restrict__ b)
{
    int row  = blockIdx.x * 4 + (threadIdx.x >> 6);
    int lane = threadIdx.x & 63;
    const float* a = A + (size_t)row * DM;
    float* h = H + (size_t)row * DM;
    float v[8];
    float s = 0.f;
    #pragma unroll
    for (int j = 0; j < 8; ++j) { v[j] = a[lane + 64 * j] + h[lane + 64 * j]; s += v[j]; }
    #pragma unroll
    for (int off = 32; off > 0; off >>= 1) s += __shfl_xor(s, off, 64);
    float mean = s * (1.0f / 512.0f);
    float var = 0.f;
    #pragma unroll
    for (int j = 0; j < 8; ++j) { float d = v[j] - mean; var += d * d; }
    #pragma unroll
    for (int off = 32; off > 0; off >>= 1) var += __shfl_xor(var, off, 64);
    float rstd = rsqrtf(var * (1.0f / 512.0f) + 1e-5f);
    #pragma unroll
    for (int j = 0; j < 8; ++j) {
        int d = lane + 64 * j;
        h[d] = (v[j] - mean) * rstd * g[d] + b[d];
    }
}

// ---------------------------------------------------------------- final projection
// out(16x3) = h.reshape(16, 524288) @ out_W(524288x3) + out_b
__global__ __launch_bounds__(256) void out_stage1(
    const float* __restrict__ h, const float* __restrict__ W,
    float* __restrict__ partial)
{
    int b = blockIdx.x, s = blockIdx.y;   // 16 x 64
    int tid = threadIdx.x;
    const float* hb = h + (size_t)b * (TSEQ * DM) + (size_t)s * 8192;
    const float* Wb = W + (size_t)s * 8192 * 3;
    float a0 = 0.f, a1 = 0.f, a2 = 0.f;
    #pragma unroll 4
    for (int it = 0; it < 32; ++it) {
        int i = it * 256 + tid;
        float hv = hb[i];
        a0 += hv * Wb[i * 3 + 0];
        a1 += hv * Wb[i * 3 + 1];
        a2 += hv * Wb[i * 3 + 2];
    }
    __shared__ float red[3][256];
    red[0][tid] = a0; red[1][tid] = a1; red[2][tid] = a2;
    __syncthreads();
    for (int off = 128; off > 0; off >>= 1) {
        if (tid < off) {
            red[0][tid] += red[0][tid + off];
            red[1][tid] += red[1][tid + off];
            red[2][tid] += red[2][tid + off];
        }
        __syncthreads();
    }
    if (tid == 0) {
        partial[(b * 64 + s) * 3 + 0] = red[0][0];
        partial[(b * 64 + s) * 3 + 1] = red[1][0];
        partial[(b * 64 + s) * 3 + 2] = red[2][0];
    }
}

__global__ __launch_bounds__(64) void out_stage2(
    const float* __restrict__ partial, const float* __restrict__ ob,
    float* __restrict__ out)
{
    int t = threadIdx.x;
    if (t < NB * DOUTN) {
        int b = t / 3, o = t % 3;
        float s = ob[o];
        for (int k = 0; k < 64; ++k) s += partial[(b * 64 + k) * 3 + o];
        out[t] = s;   // t == b*3 + o
    }
}

// ---------------------------------------------------------------- launch
extern "C" void kernel_launch(void* const* d_in, const int* in_sizes, int n_in,
                              void* d_out, int out_size, void* d_ws, size_t ws_size,
                              hipStream_t stream)
{
    const float* x    = (const float*)d_in[0];
    const int*   pad  = (const int*)  d_in[1];
    const float* encW = (const float*)d_in[2];
    const float* encB = (const float*)d_in[3];
    const float* Wq   = (const float*)d_in[4];
    const float* Wk   = (const float*)d_in[5];
    const float* Wv   = (const float*)d_in[6];
    const float* Wo   = (const float*)d_in[7];
    const float* fW1  = (const float*)d_in[8];
    const float* fb1  = (const float*)d_in[9];
    const float* fW2  = (const float*)d_in[10];
    const float* fb2  = (const float*)d_in[11];
    const float* l1g  = (const float*)d_in[12];
    const float* l1b  = (const float*)d_in[13];
    const float* l2g  = (const float*)d_in[14];
    const float* l2b  = (const float*)d_in[15];
    const float* outW = (const float*)d_in[16];
    const float* outB = (const float*)d_in[17];
    float* out = (float*)d_out;

    // workspace: h(8M) | bq(8M) | bk(8M) | bv(8M) floats = 128 MB
    const size_t BUF = (size_t)ROWS * DM;          // 8,388,608 floats
    if (ws_size < 4 * BUF * sizeof(float)) return; // insufficient scratch
    float* ws = (float*)d_ws;
    float* h  = ws;
    float* bq = ws + BUF;
    float* bk = ws + 2 * BUF;
    float* bv = ws + 3 * BUF;

    encode_kernel<<<ROWS, 128, 0, stream>>>(x, pad, encW, encB, h);

    for (int l = 0; l < NLAYERS; ++l) {
        const float* wq = Wq + (size_t)l * DM * DM;
        const float* wk = Wk + (size_t)l * DM * DM;
        const float* wv = Wv + (size_t)l * DM * DM;
        const float* wo = Wo + (size_t)l * DM * DM;
        dim3 g512(ROWS / 64, DM / 64);
        gemm_f32<0><<<g512, 256, 0, stream>>>(h,  wq, nullptr, bq, ROWS, DM, DM);
        gemm_f32<0><<<g512, 256, 0, stream>>>(h,  wk, nullptr, bk, ROWS, DM, DM);
        gemm_f32<0><<<g512, 256, 0, stream>>>(h,  wv, nullptr, bv, ROWS, DM, DM);
        attn_kernel<<<ROWS, 64, 0, stream>>>(bq, bk, bv, pad, bv);   // O in-place over V
        gemm_f32<0><<<g512, 256, 0, stream>>>(bv, wo, nullptr, bq, ROWS, DM, DM);
        add_ln_kernel<<<ROWS / 4, 256, 0, stream>>>(bq, h, l1g + l * DM, l1b + l * DM);
        // FFN in 4 M-chunks of 4096 rows (mid = 4096x2048 fits in bk)
        for (int c = 0; c < 4; ++c) {
            float* hc = h + (size_t)c * 4096 * DM;
            gemm_f32<1><<<dim3(64, DFFN / 64), 256, 0, stream>>>(
                hc, fW1 + (size_t)l * DM * DFFN, fb1 + (size_t)l * DFFN, bk, 4096, DFFN, DM);
            gemm_f32<0><<<dim3(64, DM / 64), 256, 0, stream>>>(
                bk, fW2 + (size_t)l * DFFN * DM, fb2 + (size_t)l * DM, bv, 4096, DM, DFFN);
            add_ln_kernel<<<1024, 256, 0, stream>>>(bv, hc, l2g + l * DM, l2b + l * DM);
        }
    }

    out_stage1<<<dim3(NB, 64), 256, 0, stream>>>(h, outW, bq);
    out_stage2<<<1, 64, 0, stream>>>(bq, outB, out);
}

// Round 2
// 1080.145 us; speedup vs baseline: 6.5455x; 6.5455x over previous
//
#include <hip/hip_runtime.h>
#include <cmath>

#define NB 16
#define TSEQ 1024
#define DIN 16
#define DM 512
#define DFFN 2048
#define NLAYERS 4
#define DOUTN 3
#define ROWS (NB*TSEQ)   /* 16384 */

typedef unsigned short u16;
typedef short bf16x8 __attribute__((ext_vector_type(8)));
typedef u16   u16x4  __attribute__((ext_vector_type(4)));
typedef float f32x4  __attribute__((ext_vector_type(4)));

__device__ __forceinline__ float b2f(u16 v) { return __uint_as_float((unsigned)v << 16); }
__device__ __forceinline__ u16 f2b(float f) {
    unsigned u = __float_as_uint(f);
    return (u16)((u + 0x7FFFu + ((u >> 16) & 1u)) >> 16);
}

#define GLL(gp, lp) __builtin_amdgcn_global_load_lds( \
    (const __attribute__((address_space(1))) unsigned int*)(gp), \
    (__attribute__((address_space(3))) unsigned int*)(lp), 16, 0, 0)

// ------------------------------------------------- weight transpose + cast
// out[n][k] = (bf16) in[k][n];  in: [K][N] f32 (per layer), out: [N][K] bf16
__global__ __launch_bounds__(256) void transpose_cast(
    const float* __restrict__ in, u16* __restrict__ out,
    int K, int N, size_t in_lstride, size_t out_lstride)
{
    in  += (size_t)blockIdx.z * in_lstride;
    out += (size_t)blockIdx.z * out_lstride;
    __shared__ float t[32][33];
    int bk = blockIdx.x * 32, bn = blockIdx.y * 32;
    int x = threadIdx.x & 31, y = threadIdx.x >> 5;   // y: 0..7
    #pragma unroll
    for (int i = 0; i < 32; i += 8)
        t[y + i][x] = in[(size_t)(bk + y + i) * N + bn + x];
    __syncthreads();
    #pragma unroll
    for (int i = 0; i < 32; i += 8)
        out[(size_t)(bn + y + i) * K + bk + x] = f2b(t[x][y + i]);
}

// ------------------------------------------------- encode (bf16 out)
__global__ __launch_bounds__(128) void encode_kernel(
    const float* __restrict__ x, const int* __restrict__ pad,
    const float* __restrict__ W, const float* __restrict__ b,
    u16* __restrict__ h)
{
    int row = blockIdx.x;          // row = batch*1024 + t
    int t   = row & (TSEQ - 1);
    int c   = threadIdx.x * 4;
    float acc[4];
    #pragma unroll
    for (int j = 0; j < 4; ++j) acc[j] = b[c + j];
    const float* xr = x + (size_t)row * DIN;
    #pragma unroll
    for (int k = 0; k < DIN; ++k) {
        float xv = xr[k];
        const float* wr = W + (size_t)k * DM + c;
        #pragma unroll
        for (int j = 0; j < 4; ++j) acc[j] += xv * wr[j];
    }
    const float s = 22.62741699796952f;  // sqrt(512)
    bool has_pe = (pad[row] != 0);
    u16x4 o;
    #pragma unroll
    for (int j = 0; j < 4; ++j) {
        acc[j] *= s;
        if (has_pe) {
            int d = c + j;
            float base = (float)t * powf(10000.0f, -(float)d * (1.0f/512.0f));
            acc[j] += ((d & 1) == 0) ? sinf(base) : cosf(base);
        }
        o[j] = f2b(acc[j]);
    }
    *(u16x4*)&h[(size_t)row * DM + c] = o;
}

// ------------------------------------------------- bf16 MFMA GEMM (m97 structure)
// C(MxN) = A(MxK) @ Bt(NxK)^T [+bias] [relu], all bf16, fp32 accum.
// 128x128 tile, BK=32, 256 thr = 4 waves (2x2), 64x64 per wave.
template<int BIAS, int RELU>
__global__ __launch_bounds__(256) void gemm_bf16(
    const u16* __restrict__ A, const u16* __restrict__ Bt,
    const float* __restrict__ bias, u16* __restrict__ C,
    int M, int N, int K)
{
    __shared__ u16 As[128 * 32];
    __shared__ u16 Bs[128 * 32];
    const int tid  = threadIdx.x;
    const int lane = tid & 63;
    const int wid  = tid >> 6;
    const int wr   = wid >> 1, wc = wid & 1;
    const int bm   = blockIdx.x * 128;
    const int bn   = blockIdx.y * 128;

    // staging addresses: wave w stages rows w*32..w*32+31 of each tile (2 issues)
    const int srow = lane >> 2;          // 0..15
    const int scol = (lane & 3) * 8;     // 0,8,16,24  (bf16 elems; 16B per lane)
    const u16* Ag0 = A  + (size_t)(bm + wid * 32 + srow) * K + scol;
    const u16* Ag1 = Ag0 + (size_t)16 * K;
    const u16* Bg0 = Bt + (size_t)(bn + wid * 32 + srow) * K + scol;
    const u16* Bg1 = Bg0 + (size_t)16 * K;
    u16* Al = As + wid * 1024;           // element index; issue1 at +512
    u16* Bl = Bs + wid * 1024;

    f32x4 acc[4][4];
    #pragma unroll
    for (int m = 0; m < 4; ++m)
        #pragma unroll
        for (int n = 0; n < 4; ++n)
            acc[m][n] = (f32x4){0.f, 0.f, 0.f, 0.f};

    const int fr = lane & 15;            // frag row/col index
    const int fk = (lane >> 4) * 8;      // frag K offset

    for (int k0 = 0; k0 < K; k0 += 32) {
        GLL(Ag0 + k0, Al);
        GLL(Ag1 + k0, Al + 512);
        GLL(Bg0 + k0, Bl);
        GLL(Bg1 + k0, Bl + 512);
        __syncthreads();
        bf16x8 a[4], b[4];
        #pragma unroll
        for (int m = 0; m < 4; ++m)
            a[m] = *(const bf16x8*)(As + (size_t)(wr * 64 + m * 16 + fr) * 32 + fk);
        #pragma unroll
        for (int n = 0; n < 4; ++n)
            b[n] = *(const bf16x8*)(Bs + (size_t)(wc * 64 + n * 16 + fr) * 32 + fk);
        #pragma unroll
        for (int m = 0; m < 4; ++m)
            #pragma unroll
            for (int n = 0; n < 4; ++n)
                acc[m][n] = __builtin_amdgcn_mfma_f32_16x16x32_bf16(a[m], b[n], acc[m][n], 0, 0, 0);
        __syncthreads();
    }

    float bb[4] = {0.f, 0.f, 0.f, 0.f};
    if (BIAS) {
        #pragma unroll
        for (int n = 0; n < 4; ++n) bb[n] = bias[bn + wc * 64 + n * 16 + fr];
    }
    #pragma unroll
    for (int m = 0; m < 4; ++m) {
        #pragma unroll
        for (int n = 0; n < 4; ++n) {
            int col = bn + wc * 64 + n * 16 + fr;
            #pragma unroll
            for (int j = 0; j < 4; ++j) {
                int row = bm + wr * 64 + m * 16 + ((lane >> 4) << 2) + j;
                float v = acc[m][n][j];
                if (BIAS) v += bb[n];
                if (RELU) v = fmaxf(v, 0.f);
                C[(size_t)row * N + col] = f2b(v);
            }
        }
    }
}

// ------------------------------------------------- attention (per token, 1 wave)
// qkv: [row][1536] bf16 = Q|K|V.  energy(64x64)=Qh@Kh/32, mask, softmax, @Vh.
__global__ __launch_bounds__(64) void attn_kernel(
    const u16* __restrict__ QKV, const int* __restrict__ pad,
    u16* __restrict__ O)
{
    int site = blockIdx.x;
    int lane = threadIdx.x;
    __shared__ float qs[512], ks[512], vs[512];
    const u16* base = QKV + (size_t)site * 1536;
    bf16x8 qv = *(const bf16x8*)(base + lane * 8);
    bf16x8 kv = *(const bf16x8*)(base + 512 + lane * 8);
    bf16x8 vv = *(const bf16x8*)(base + 1024 + lane * 8);
    #pragma unroll
    for (int j = 0; j < 8; ++j) {
        qs[lane * 8 + j] = b2f((u16)qv[j]);
        ks[lane * 8 + j] = b2f((u16)kv[j]);
        vs[lane * 8 + j] = b2f((u16)vv[j]);
    }
    __syncthreads();
    float qr[8];
    #pragma unroll
    for (int j = 0; j < 8; ++j) qr[j] = qs[j * 64 + lane];
    float e[64];
    float m = -1e30f;
    #pragma unroll
    for (int k2 = 0; k2 < 64; ++k2) {
        float s = 0.f;
        #pragma unroll
        for (int j = 0; j < 8; ++j) s += qr[j] * ks[j * 64 + k2];
        s *= (1.0f / 32.0f);
        e[k2] = s;
        m = fmaxf(m, s);
    }
    bool masked = (pad[site] == 0);
    float sum = 0.f;
    #pragma unroll
    for (int k2 = 0; k2 < 64; ++k2) {
        float p = masked ? 1.0f : __expf(e[k2] - m);
        e[k2] = p;
        sum += p;
    }
    float inv = 1.0f / sum;
    float o[8] = {0.f,0.f,0.f,0.f,0.f,0.f,0.f,0.f};
    #pragma unroll
    for (int k2 = 0; k2 < 64; ++k2) {
        float p = e[k2] * inv;
        #pragma unroll
        for (int j = 0; j < 8; ++j) o[j] += p * vs[j * 64 + k2];
    }
    bf16x8 ov;
    #pragma unroll
    for (int j = 0; j < 8; ++j) ov[j] = (short)f2b(o[j]);
    *(bf16x8*)(O + (size_t)site * DM + lane * 8) = ov;
}

// ------------------------------------------------- residual add + layernorm (bf16)
__global__ __launch_bounds__(256) void add_ln_kernel(
    const u16* __restrict__ A, u16* __restrict__ H,
    const float* __restrict__ g, const float* __restrict__ b)
{
    int row  = blockIdx.x * 4 + (threadIdx.x >> 6);
    int lane = threadIdx.x & 63;
    const u16* a = A + (size_t)row * DM + lane * 8;
    u16* h = H + (size_t)row * DM + lane * 8;
    bf16x8 av = *(const bf16x8*)a;
    bf16x8 hv = *(const bf16x8*)h;
    float v[8];
    float s = 0.f;
    #pragma unroll
    for (int j = 0; j < 8; ++j) { v[j] = b2f((u16)av[j]) + b2f((u16)hv[j]); s += v[j]; }
    #pragma unroll
    for (int off = 32; off > 0; off >>= 1) s += __shfl_xor(s, off, 64);
    float mean = s * (1.0f / 512.0f);
    float var = 0.f;
    #pragma unroll
    for (int j = 0; j < 8; ++j) { float d = v[j] - mean; var += d * d; }
    #pragma unroll
    for (int off = 32; off > 0; off >>= 1) var += __shfl_xor(var, off, 64);
    float rstd = rsqrtf(var * (1.0f / 512.0f) + 1e-5f);
    bf16x8 ov;
    #pragma unroll
    for (int j = 0; j < 8; ++j) {
        int d = lane * 8 + j;
        ov[j] = (short)f2b((v[j] - mean) * rstd * g[d] + b[d]);
    }
    *(bf16x8*)h = ov;
}

// ------------------------------------------------- final projection
__global__ __launch_bounds__(256) void out_stage1(
    const u16* __restrict__ h, const float* __restrict__ W,
    float* __restrict__ partial)
{
    int b = blockIdx.x, s = blockIdx.y;   // 16 x 64
    int tid = threadIdx.x;
    const u16* hb = h + (size_t)b * (TSEQ * DM) + (size_t)s * 8192;
    const float* Wb = W + (size_t)s * 8192 * 3;
    float a0 = 0.f, a1 = 0.f, a2 = 0.f;
    #pragma unroll 4
    for (int it = 0; it < 32; ++it) {
        int i = it * 256 + tid;
        float hv = b2f(hb[i]);
        a0 += hv * Wb[i * 3 + 0];
        a1 += hv * Wb[i * 3 + 1];
        a2 += hv * Wb[i * 3 + 2];
    }
    __shared__ float red[3][256];
    red[0][tid] = a0; red[1][tid] = a1; red[2][tid] = a2;
    __syncthreads();
    for (int off = 128; off > 0; off >>= 1) {
        if (tid < off) {
            red[0][tid] += red[0][tid + off];
            red[1][tid] += red[1][tid + off];
            red[2][tid] += red[2][tid + off];
        }
        __syncthreads();
    }
    if (tid == 0) {
        partial[(b * 64 + s) * 3 + 0] = red[0][0];
        partial[(b * 64 + s) * 3 + 1] = red[1][0];
        partial[(b * 64 + s) * 3 + 2] = red[2][0];
    }
}

__global__ __launch_bounds__(64) void out_stage2(
    const float* __restrict__ partial, const float* __restrict__ ob,
    float* __restrict__ out)
{
    int t = threadIdx.x;
    if (t < NB * DOUTN) {
        int b = t / 3, o = t % 3;
        float s = ob[o];
        for (int k = 0; k < 64; ++k) s += partial[(b * 64 + k) * 3 + o];
        out[t] = s;
    }
}

// ------------------------------------------------- launch
extern "C" void kernel_launch(void* const* d_in, const int* in_sizes, int n_in,
                              void* d_out, int out_size, void* d_ws, size_t ws_size,
                              hipStream_t stream)
{
    const float* x    = (const float*)d_in[0];
    const int*   pad  = (const int*)  d_in[1];
    const float* encW = (const float*)d_in[2];
    const float* encB = (const float*)d_in[3];
    const float* Wq   = (const float*)d_in[4];
    const float* Wk   = (const float*)d_in[5];
    const float* Wv   = (const float*)d_in[6];
    const float* Wo   = (const float*)d_in[7];
    const float* fW1  = (const float*)d_in[8];
    const float* fb1  = (const float*)d_in[9];
    const float* fW2  = (const float*)d_in[10];
    const float* fb2  = (const float*)d_in[11];
    const float* l1g  = (const float*)d_in[12];
    const float* l1b  = (const float*)d_in[13];
    const float* l2g  = (const float*)d_in[14];
    const float* l2b  = (const float*)d_in[15];
    const float* outW = (const float*)d_in[16];
    const float* outB = (const float*)d_in[17];
    float* out = (float*)d_out;

    // workspace (u16 elements):
    //   wt: 4 layers x [wq_t|wk_t|wv_t|wo_t|w1_t|w2_t] = 4 x 3,145,728
    //   h:  16384x512 ; b0..b4: 16384x512 each (FF1 mid overlays b0..b3)
    const size_t WL  = 3145728;
    const size_t BUF = (size_t)ROWS * DM;      // 8,388,608 u16
    const size_t need = (4 * WL + 6 * BUF) * sizeof(u16);   // 125,829,120 B
    if (ws_size < need) return;
    u16* wt = (u16*)d_ws;
    u16* h  = wt + 4 * WL;
    u16* b0 = h  + BUF;
    u16* b3 = b0 + 3 * BUF;
    u16* b4 = b3 + BUF;

    // ---- weight prep (bf16, transposed [N][K]); Wq|Wk|Wv packed for fused QKV
    transpose_cast<<<dim3(16,16,4), 256, 0, stream>>>(Wq,  wt + 0,       512,  512,  (size_t)512*512,  WL);
    transpose_cast<<<dim3(16,16,4), 256, 0, stream>>>(Wk,  wt + 262144,  512,  512,  (size_t)512*512,  WL);
    transpose_cast<<<dim3(16,16,4), 256, 0, stream>>>(Wv,  wt + 524288,  512,  512,  (size_t)512*512,  WL);
    transpose_cast<<<dim3(16,16,4), 256, 0, stream>>>(Wo,  wt + 786432,  512,  512,  (size_t)512*512,  WL);
    transpose_cast<<<dim3(16,64,4), 256, 0, stream>>>(fW1, wt + 1048576, 512,  2048, (size_t)512*2048, WL);
    transpose_cast<<<dim3(64,16,4), 256, 0, stream>>>(fW2, wt + 2097152, 2048, 512,  (size_t)2048*512, WL);

    encode_kernel<<<ROWS, 128, 0, stream>>>(x, pad, encW, encB, h);

    for (int l = 0; l < NLAYERS; ++l) {
        u16* wl = wt + (size_t)l * WL;
        // fused QKV: C[16384][1536] -> b0..b2
        gemm_bf16<0,0><<<dim3(128,12), 256, 0, stream>>>(h, wl, nullptr, b0, ROWS, 1536, DM);
        attn_kernel<<<ROWS, 64, 0, stream>>>(b0, pad, b3);
        // O-projection -> b4
        gemm_bf16<0,0><<<dim3(128,4), 256, 0, stream>>>(b3, wl + 786432, nullptr, b4, ROWS, DM, DM);
        add_ln_kernel<<<ROWS/4, 256, 0, stream>>>(b4, h, l1g + l*DM, l1b + l*DM);
        // FFN full-M: mid [16384][2048] overlays b0..b3
        gemm_bf16<1,1><<<dim3(128,16), 256, 0, stream>>>(h, wl + 1048576, fb1 + (size_t)l*DFFN, b0, ROWS, DFFN, DM);
        gemm_bf16<1,0><<<dim3(128,4),  256, 0, stream>>>(b0, wl + 2097152, fb2 + (size_t)l*DM, b4, ROWS, DM, DFFN);
        add_ln_kernel<<<ROWS/4, 256, 0, stream>>>(b4, h, l2g + l*DM, l2b + l*DM);
    }

    out_stage1<<<dim3(NB, 64), 256, 0, stream>>>(h, outW, (float*)b0);
    out_stage2<<<1, 64, 0, stream>>>((float*)b0, outB, out);
}

// Round 3
// 967.264 us; speedup vs baseline: 7.3094x; 1.1167x over previous
//
#include <hip/hip_runtime.h>
#include <cmath>

#define NB 16
#define TSEQ 1024
#define DIN 16
#define DM 512
#define DFFN 2048
#define NLAYERS 4
#define DOUTN 3
#define ROWS (NB*TSEQ)   /* 16384 */

typedef unsigned short u16;
typedef short bf16x8 __attribute__((ext_vector_type(8)));
typedef u16   u16x4  __attribute__((ext_vector_type(4)));
typedef float f32x4  __attribute__((ext_vector_type(4)));

__device__ __forceinline__ float b2f(u16 v) { return __uint_as_float((unsigned)v << 16); }
__device__ __forceinline__ u16 f2b(float f) {
    unsigned u = __float_as_uint(f);
    return (u16)((u + 0x7FFFu + ((u >> 16) & 1u)) >> 16);
}

#define GLL(gp, lp) __builtin_amdgcn_global_load_lds( \
    (const __attribute__((address_space(1))) unsigned int*)(gp), \
    (__attribute__((address_space(3))) unsigned int*)(lp), 16, 0, 0)

// ------------------------------------------------- weight transpose + cast
__global__ __launch_bounds__(256) void transpose_cast(
    const float* __restrict__ in, u16* __restrict__ out,
    int K, int N, size_t in_lstride, size_t out_lstride)
{
    in  += (size_t)blockIdx.z * in_lstride;
    out += (size_t)blockIdx.z * out_lstride;
    __shared__ float t[32][33];
    int bk = blockIdx.x * 32, bn = blockIdx.y * 32;
    int x = threadIdx.x & 31, y = threadIdx.x >> 5;
    #pragma unroll
    for (int i = 0; i < 32; i += 8)
        t[y + i][x] = in[(size_t)(bk + y + i) * N + bn + x];
    __syncthreads();
    #pragma unroll
    for (int i = 0; i < 32; i += 8)
        out[(size_t)(bn + y + i) * K + bk + x] = f2b(t[x][y + i]);
}

// ------------------------------------------------- encode (bf16 out)
__global__ __launch_bounds__(128) void encode_kernel(
    const float* __restrict__ x, const int* __restrict__ pad,
    const float* __restrict__ W, const float* __restrict__ b,
    u16* __restrict__ h)
{
    int row = blockIdx.x;
    int t   = row & (TSEQ - 1);
    int c   = threadIdx.x * 4;
    float acc[4];
    #pragma unroll
    for (int j = 0; j < 4; ++j) acc[j] = b[c + j];
    const float* xr = x + (size_t)row * DIN;
    #pragma unroll
    for (int k = 0; k < DIN; ++k) {
        float xv = xr[k];
        const float* wr = W + (size_t)k * DM + c;
        #pragma unroll
        for (int j = 0; j < 4; ++j) acc[j] += xv * wr[j];
    }
    const float s = 22.62741699796952f;
    bool has_pe = (pad[row] != 0);
    u16x4 o;
    #pragma unroll
    for (int j = 0; j < 4; ++j) {
        acc[j] *= s;
        if (has_pe) {
            int d = c + j;
            float base = (float)t * powf(10000.0f, -(float)d * (1.0f/512.0f));
            acc[j] += ((d & 1) == 0) ? sinf(base) : cosf(base);
        }
        o[j] = f2b(acc[j]);
    }
    *(u16x4*)&h[(size_t)row * DM + c] = o;
}

// ------------------------------------------------- bf16 MFMA GEMM (m97 structure)
template<int BIAS, int RELU>
__global__ __launch_bounds__(256) void gemm_bf16(
    const u16* __restrict__ A, const u16* __restrict__ Bt,
    const float* __restrict__ bias, u16* __restrict__ C,
    int M, int N, int K)
{
    __shared__ u16 As[128 * 32];
    __shared__ u16 Bs[128 * 32];
    const int tid  = threadIdx.x;
    const int lane = tid & 63;
    const int wid  = tid >> 6;
    const int wr   = wid >> 1, wc = wid & 1;
    const int bm   = blockIdx.x * 128;
    const int bn   = blockIdx.y * 128;

    const int srow = lane >> 2;
    const int scol = (lane & 3) * 8;
    const u16* Ag0 = A  + (size_t)(bm + wid * 32 + srow) * K + scol;
    const u16* Ag1 = Ag0 + (size_t)16 * K;
    const u16* Bg0 = Bt + (size_t)(bn + wid * 32 + srow) * K + scol;
    const u16* Bg1 = Bg0 + (size_t)16 * K;
    u16* Al = As + wid * 1024;
    u16* Bl = Bs + wid * 1024;

    f32x4 acc[4][4];
    #pragma unroll
    for (int m = 0; m < 4; ++m)
        #pragma unroll
        for (int n = 0; n < 4; ++n)
            acc[m][n] = (f32x4){0.f, 0.f, 0.f, 0.f};

    const int fr = lane & 15;
    const int fk = (lane >> 4) * 8;

    for (int k0 = 0; k0 < K; k0 += 32) {
        GLL(Ag0 + k0, Al);
        GLL(Ag1 + k0, Al + 512);
        GLL(Bg0 + k0, Bl);
        GLL(Bg1 + k0, Bl + 512);
        __syncthreads();
        bf16x8 a[4], b[4];
        #pragma unroll
        for (int m = 0; m < 4; ++m)
            a[m] = *(const bf16x8*)(As + (size_t)(wr * 64 + m * 16 + fr) * 32 + fk);
        #pragma unroll
        for (int n = 0; n < 4; ++n)
            b[n] = *(const bf16x8*)(Bs + (size_t)(wc * 64 + n * 16 + fr) * 32 + fk);
        #pragma unroll
        for (int m = 0; m < 4; ++m)
            #pragma unroll
            for (int n = 0; n < 4; ++n)
                acc[m][n] = __builtin_amdgcn_mfma_f32_16x16x32_bf16(a[m], b[n], acc[m][n], 0, 0, 0);
        __syncthreads();
    }

    float bb[4] = {0.f, 0.f, 0.f, 0.f};
    if (BIAS) {
        #pragma unroll
        for (int n = 0; n < 4; ++n) bb[n] = bias[bn + wc * 64 + n * 16 + fr];
    }
    #pragma unroll
    for (int m = 0; m < 4; ++m) {
        #pragma unroll
        for (int n = 0; n < 4; ++n) {
            int col = bn + wc * 64 + n * 16 + fr;
            #pragma unroll
            for (int j = 0; j < 4; ++j) {
                int row = bm + wr * 64 + m * 16 + ((lane >> 4) << 2) + j;
                float v = acc[m][n][j];
                if (BIAS) v += bb[n];
                if (RELU) v = fmaxf(v, 0.f);
                C[(size_t)row * N + col] = f2b(v);
            }
        }
    }
}

// ------------------------------------------------- attention (MFMA, 1 wave/token)
// QKV row [1536] = Q|K|V, each flat [h=8][dh=64] (index h*64+dh).
// energy[i][j] = sum_h Q[h*64+i]*K[h*64+j]; out[i][h] = sum_k P[i][k]*V[h*64+k];
// O flat index = i*8 + h.
__global__ __launch_bounds__(256) void attn_mfma(
    const u16* __restrict__ QKV, const int* __restrict__ pad,
    u16* __restrict__ O)
{
    // per-wave LDS: Q 512 | K 512 | V 8x72=576 | P 4096 | Ostage 512 = 6208 u16
    constexpr int WLDS = 6208;
    __shared__ u16 sh[4 * WLDS];
    const int wid  = threadIdx.x >> 6;
    const int lane = threadIdx.x & 63;
    const int site = blockIdx.x * 4 + wid;
    u16* Ql = sh + wid * WLDS;
    u16* Kl = Ql + 512;
    u16* Vl = Ql + 1024;
    u16* P  = Ql + 1600;
    u16* Ol = Ql + 5696;

    const u16* base = QKV + (size_t)site * 1536;
    *(bf16x8*)(Ql + lane * 8) = *(const bf16x8*)(base + lane * 8);
    *(bf16x8*)(Kl + lane * 8) = *(const bf16x8*)(base + 512 + lane * 8);
    {   // V with row stride 72 (bank de-conflict for B-frag reads)
        bf16x8 v = *(const bf16x8*)(base + 1024 + lane * 8);
        *(bf16x8*)(Vl + (lane >> 3) * 72 + (lane & 7) * 8) = v;
    }

    const int fr  = lane & 15;
    const int grp = lane >> 4;           // 0..3
    const bool masked = (pad[site] == 0);
    const bf16x8 zb = {0,0,0,0,0,0,0,0};
    const f32x4  zf = {0.f,0.f,0.f,0.f};

    if (masked) {
        // uniform attn = 1/64 everywhere
        const u16 c = f2b(1.0f / 64.0f);
        bf16x8 cv = {(short)c,(short)c,(short)c,(short)c,(short)c,(short)c,(short)c,(short)c};
        #pragma unroll
        for (int i = 0; i < 8; ++i)
            *(bf16x8*)(P + i * 512 + lane * 8) = cv;
    } else {
        // A/B fragments for QK^T: lanes 0-15 carry k=0..7, rest zero (K-pad)
        bf16x8 aq[4], bk[4];
        #pragma unroll
        for (int m = 0; m < 4; ++m) { aq[m] = zb; bk[m] = zb; }
        if (grp == 0) {
            #pragma unroll
            for (int m = 0; m < 4; ++m)
                #pragma unroll
                for (int j = 0; j < 8; ++j) {
                    aq[m][j] = (short)Ql[j * 64 + m * 16 + fr];
                    bk[m][j] = (short)Kl[j * 64 + m * 16 + fr];
                }
        }
        #pragma unroll
        for (int m = 0; m < 4; ++m) {
            f32x4 ev[4];
            #pragma unroll
            for (int n = 0; n < 4; ++n)
                ev[n] = __builtin_amdgcn_mfma_f32_16x16x32_bf16(aq[m], bk[n], zf, 0, 0, 0);
            #pragma unroll
            for (int j = 0; j < 4; ++j) {
                float v = fmaxf(fmaxf(ev[0][j], ev[1][j]), fmaxf(ev[2][j], ev[3][j]));
                v = fmaxf(v, __shfl_xor(v, 1));
                v = fmaxf(v, __shfl_xor(v, 2));
                v = fmaxf(v, __shfl_xor(v, 4));
                v = fmaxf(v, __shfl_xor(v, 8));
                float p0 = __expf((ev[0][j] - v) * 0.03125f);
                float p1 = __expf((ev[1][j] - v) * 0.03125f);
                float p2 = __expf((ev[2][j] - v) * 0.03125f);
                float p3 = __expf((ev[3][j] - v) * 0.03125f);
                float s = p0 + p1 + p2 + p3;
                s += __shfl_xor(s, 1);
                s += __shfl_xor(s, 2);
                s += __shfl_xor(s, 4);
                s += __shfl_xor(s, 8);
                float inv = 1.0f / s;
                int row = m * 16 + grp * 4 + j;
                int sw  = (row & 7) << 3;
                P[(row * 64 +  0 + fr) ^ sw] = f2b(p0 * inv);
                P[(row * 64 + 16 + fr) ^ sw] = f2b(p1 * inv);
                P[(row * 64 + 32 + fr) ^ sw] = f2b(p2 * inv);
                P[(row * 64 + 48 + fr) ^ sw] = f2b(p3 * inv);
            }
        }
    }

    // PV: out(64x16, 8 valid cols) = P(64x64) @ Vt ; B[k][h] = V[h*64+k]
    bf16x8 bv[2];
    #pragma unroll
    for (int ks = 0; ks < 2; ++ks) {
        int kb = ks * 32 + grp * 8;
        bv[ks] = (fr < 8) ? *(const bf16x8*)(Vl + fr * 72 + kb) : zb;
    }
    f32x4 pv[4];
    #pragma unroll
    for (int m = 0; m < 4; ++m) pv[m] = zf;
    #pragma unroll
    for (int m = 0; m < 4; ++m) {
        #pragma unroll
        for (int ks = 0; ks < 2; ++ks) {
            int row = m * 16 + fr;
            int off = (row * 64 + ks * 32 + grp * 8) ^ ((row & 7) << 3);
            bf16x8 ap = *(const bf16x8*)(P + off);
            pv[m] = __builtin_amdgcn_mfma_f32_16x16x32_bf16(ap, bv[ks], pv[m], 0, 0, 0);
        }
    }
    // stage output through LDS for coalesced global write: O flat = row*8 + h
    #pragma unroll
    for (int m = 0; m < 4; ++m)
        #pragma unroll
        for (int j = 0; j < 4; ++j) {
            int row = m * 16 + grp * 4 + j;
            if (fr < 8) Ol[row * 8 + fr] = f2b(pv[m][j]);
        }
    bf16x8 o = *(const bf16x8*)(Ol + lane * 8);
    *(bf16x8*)(O + (size_t)site * DM + lane * 8) = o;
}

// ------------------------------------------------- residual add + layernorm (bf16)
__global__ __launch_bounds__(256) void add_ln_kernel(
    const u16* __restrict__ A, u16* __restrict__ H,
    const float* __restrict__ g, const float* __restrict__ b)
{
    int row  = blockIdx.x * 4 + (threadIdx.x >> 6);
    int lane = threadIdx.x & 63;
    const u16* a = A + (size_t)row * DM + lane * 8;
    u16* h = H + (size_t)row * DM + lane * 8;
    bf16x8 av = *(const bf16x8*)a;
    bf16x8 hv = *(const bf16x8*)h;
    float v[8];
    float s = 0.f;
    #pragma unroll
    for (int j = 0; j < 8; ++j) { v[j] = b2f((u16)av[j]) + b2f((u16)hv[j]); s += v[j]; }
    #pragma unroll
    for (int off = 32; off > 0; off >>= 1) s += __shfl_xor(s, off, 64);
    float mean = s * (1.0f / 512.0f);
    float var = 0.f;
    #pragma unroll
    for (int j = 0; j < 8; ++j) { float d = v[j] - mean; var += d * d; }
    #pragma unroll
    for (int off = 32; off > 0; off >>= 1) var += __shfl_xor(var, off, 64);
    float rstd = rsqrtf(var * (1.0f / 512.0f) + 1e-5f);
    bf16x8 ov;
    #pragma unroll
    for (int j = 0; j < 8; ++j) {
        int d = lane * 8 + j;
        ov[j] = (short)f2b((v[j] - mean) * rstd * g[d] + b[d]);
    }
    *(bf16x8*)h = ov;
}

// ------------------------------------------------- final projection
__global__ __launch_bounds__(256) void out_stage1(
    const u16* __restrict__ h, const float* __restrict__ W,
    float* __restrict__ partial)
{
    int b = blockIdx.x, s = blockIdx.y;
    int tid = threadIdx.x;
    const u16* hb = h + (size_t)b * (TSEQ * DM) + (size_t)s * 8192;
    const float* Wb = W + (size_t)s * 8192 * 3;
    float a0 = 0.f, a1 = 0.f, a2 = 0.f;
    #pragma unroll 4
    for (int it = 0; it < 32; ++it) {
        int i = it * 256 + tid;
        float hv = b2f(hb[i]);
        a0 += hv * Wb[i * 3 + 0];
        a1 += hv * Wb[i * 3 + 1];
        a2 += hv * Wb[i * 3 + 2];
    }
    __shared__ float red[3][256];
    red[0][tid] = a0; red[1][tid] = a1; red[2][tid] = a2;
    __syncthreads();
    for (int off = 128; off > 0; off >>= 1) {
        if (tid < off) {
            red[0][tid] += red[0][tid + off];
            red[1][tid] += red[1][tid + off];
            red[2][tid] += red[2][tid + off];
        }
        __syncthreads();
    }
    if (tid == 0) {
        partial[(b * 64 + s) * 3 + 0] = red[0][0];
        partial[(b * 64 + s) * 3 + 1] = red[1][0];
        partial[(b * 64 + s) * 3 + 2] = red[2][0];
    }
}

__global__ __launch_bounds__(64) void out_stage2(
    const float* __restrict__ partial, const float* __restrict__ ob,
    float* __restrict__ out)
{
    int t = threadIdx.x;
    if (t < NB * DOUTN) {
        int b = t / 3, o = t % 3;
        float s = ob[o];
        for (int k = 0; k < 64; ++k) s += partial[(b * 64 + k) * 3 + o];
        out[t] = s;
    }
}

// ------------------------------------------------- launch
extern "C" void kernel_launch(void* const* d_in, const int* in_sizes, int n_in,
                              void* d_out, int out_size, void* d_ws, size_t ws_size,
                              hipStream_t stream)
{
    const float* x    = (const float*)d_in[0];
    const int*   pad  = (const int*)  d_in[1];
    const float* encW = (const float*)d_in[2];
    const float* encB = (const float*)d_in[3];
    const float* Wq   = (const float*)d_in[4];
    const float* Wk   = (const float*)d_in[5];
    const float* Wv   = (const float*)d_in[6];
    const float* Wo   = (const float*)d_in[7];
    const float* fW1  = (const float*)d_in[8];
    const float* fb1  = (const float*)d_in[9];
    const float* fW2  = (const float*)d_in[10];
    const float* fb2  = (const float*)d_in[11];
    const float* l1g  = (const float*)d_in[12];
    const float* l1b  = (const float*)d_in[13];
    const float* l2g  = (const float*)d_in[14];
    const float* l2b  = (const float*)d_in[15];
    const float* outW = (const float*)d_in[16];
    const float* outB = (const float*)d_in[17];
    float* out = (float*)d_out;

    const size_t WL  = 3145728;
    const size_t BUF = (size_t)ROWS * DM;
    const size_t need = (4 * WL + 6 * BUF) * sizeof(u16);
    if (ws_size < need) return;
    u16* wt = (u16*)d_ws;
    u16* h  = wt + 4 * WL;
    u16* b0 = h  + BUF;
    u16* b3 = b0 + 3 * BUF;
    u16* b4 = b3 + BUF;

    transpose_cast<<<dim3(16,16,4), 256, 0, stream>>>(Wq,  wt + 0,       512,  512,  (size_t)512*512,  WL);
    transpose_cast<<<dim3(16,16,4), 256, 0, stream>>>(Wk,  wt + 262144,  512,  512,  (size_t)512*512,  WL);
    transpose_cast<<<dim3(16,16,4), 256, 0, stream>>>(Wv,  wt + 524288,  512,  512,  (size_t)512*512,  WL);
    transpose_cast<<<dim3(16,16,4), 256, 0, stream>>>(Wo,  wt + 786432,  512,  512,  (size_t)512*512,  WL);
    transpose_cast<<<dim3(16,64,4), 256, 0, stream>>>(fW1, wt + 1048576, 512,  2048, (size_t)512*2048, WL);
    transpose_cast<<<dim3(64,16,4), 256, 0, stream>>>(fW2, wt + 2097152, 2048, 512,  (size_t)2048*512, WL);

    encode_kernel<<<ROWS, 128, 0, stream>>>(x, pad, encW, encB, h);

    for (int l = 0; l < NLAYERS; ++l) {
        u16* wl = wt + (size_t)l * WL;
        gemm_bf16<0,0><<<dim3(128,12), 256, 0, stream>>>(h, wl, nullptr, b0, ROWS, 1536, DM);
        attn_mfma<<<ROWS/4, 256, 0, stream>>>(b0, pad, b3);
        gemm_bf16<0,0><<<dim3(128,4), 256, 0, stream>>>(b3, wl + 786432, nullptr, b4, ROWS, DM, DM);
        add_ln_kernel<<<ROWS/4, 256, 0, stream>>>(b4, h, l1g + l*DM, l1b + l*DM);
        gemm_bf16<1,1><<<dim3(128,16), 256, 0, stream>>>(h, wl + 1048576, fb1 + (size_t)l*DFFN, b0, ROWS, DFFN, DM);
        gemm_bf16<1,0><<<dim3(128,4),  256, 0, stream>>>(b0, wl + 2097152, fb2 + (size_t)l*DM, b4, ROWS, DM, DFFN);
        add_ln_kernel<<<ROWS/4, 256, 0, stream>>>(b4, h, l2g + l*DM, l2b + l*DM);
    }

    out_stage1<<<dim3(NB, 64), 256, 0, stream>>>(h, outW, (float*)b0);
    out_stage2<<<1, 64, 0, stream>>>((float*)b0, outB, out);
}